// Round 4
// baseline (1581.428 us; speedup 1.0000x reference)
//
#include <hip/hip_runtime.h>
#include <cstddef>

#define F 128
#define BM 64
#define EPSV 1e-5f
#define NBMAX 1024   // padded bucket count; NB = ceil(n/128)
#define CHUNK 8192   // edges per binfill block
#define EPT 32       // edges per thread in binfill (CHUNK/256)

__device__ inline unsigned short f2bf(float v) {  // RNE f32->bf16
  unsigned u = __float_as_uint(v);
  return (unsigned short)((u + 0x7fffu + ((u >> 16) & 1u)) >> 16);
}

// ---- zero deg, bucketCnt, BN stat accumulators ----
__global__ __launch_bounds__(256) void k_zero(int* __restrict__ deg,
                                              int* __restrict__ bucketCnt,
                                              float* __restrict__ stats, int n) {
  int i = blockIdx.x * 256 + threadIdx.x;
  if (i < n) deg[i] = 0;
  if (i < NBMAX) bucketCnt[i] = 0;
  if (i < 256) stats[i] = 0.0f;
}

// ---- in-degree count over edge targets ----
__global__ __launch_bounds__(256) void k_degc(const int* __restrict__ col,
                                              int* __restrict__ deg, int e) {
  int i = blockIdx.x * 256 + threadIdx.x;
  if (i < e) atomicAdd(&deg[col[i]], 1);
}

// ---- per-bucket degree sums (128 nodes/bucket) + dinv = rsqrt(1+deg) ----
__global__ __launch_bounds__(128) void k_bsum(const int* __restrict__ deg,
                                              int* __restrict__ bucketCnt,
                                              float* __restrict__ dinv, int n) {
  __shared__ int sb[128];
  int t = threadIdx.x;
  int gid = blockIdx.x * 128 + t;
  int d = (gid < n) ? deg[gid] : 0;
  if (gid < n) dinv[gid] = rsqrtf((float)(1 + d));
  sb[t] = d;
  __syncthreads();
  for (int off = 64; off > 0; off >>= 1) {
    if (t < off) sb[t] += sb[t + off];
    __syncthreads();
  }
  if (t == 0) bucketCnt[blockIdx.x] = sb[0];
}

// ---- single-block scan of bucketCnt -> bucketBase (exclusive) + cursor ----
__global__ __launch_bounds__(256) void k_bscan(const int* __restrict__ bucketCnt,
                                               int* __restrict__ bucketBase,
                                               int* __restrict__ gcur, int e, int nb) {
  __shared__ int sc[NBMAX];
  int t = threadIdx.x;
#pragma unroll
  for (int j = 0; j < 4; ++j) sc[t + j * 256] = bucketCnt[t + j * 256];
  __syncthreads();
  for (int off = 1; off < NBMAX; off <<= 1) {
    int v[4];
#pragma unroll
    for (int j = 0; j < 4; ++j) { int i = t + j * 256; v[j] = (i >= off) ? sc[i - off] : 0; }
    __syncthreads();
#pragma unroll
    for (int j = 0; j < 4; ++j) sc[t + j * 256] += v[j];
    __syncthreads();
  }
#pragma unroll
  for (int j = 0; j < 4; ++j) {
    int i = t + j * 256;
    int ex = sc[i] - bucketCnt[i];
    bucketBase[i] = ex;
    gcur[i] = ex;
  }
  if (t == 0) bucketBase[nb] = e;
}

// ---- LDS-staged multi-split: bin edges by target bucket, burst writes ----
// pairs[pos] = (src << 7) | (col & 127), grouped by bucket (order arbitrary)
__global__ __launch_bounds__(256) void k_binfill(const int* __restrict__ row,
                                                 const int* __restrict__ col,
                                                 int* __restrict__ gcur,
                                                 unsigned* __restrict__ pairs, int e) {
  __shared__ unsigned staged[CHUNK];        // 32 KB
  __shared__ unsigned short sbid[CHUNK];    // 16 KB
  __shared__ int cnt[NBMAX];                // 4 KB
  __shared__ int scan[NBMAX];               // 4 KB
  int t = threadIdx.x;
  int base0 = blockIdx.x * CHUNK;
  int valid = e - base0; if (valid > CHUNK) valid = CHUNK;
#pragma unroll
  for (int j = 0; j < 4; ++j) cnt[t + j * 256] = 0;
  __syncthreads();
  unsigned myb[EPT];   // bucket id
  unsigned mysl[EPT];  // (seq << 7) | colLow
#pragma unroll
  for (int k = 0; k < EPT; ++k) {
    int i = t + k * 256;
    if (i < valid) {
      int c = col[base0 + i];
      int b = c >> 7;
      int seq = atomicAdd(&cnt[b], 1);
      myb[k] = (unsigned)b;
      mysl[k] = ((unsigned)seq << 7) | (unsigned)(c & 127);
    }
  }
  __syncthreads();
#pragma unroll
  for (int j = 0; j < 4; ++j) scan[t + j * 256] = cnt[t + j * 256];
  __syncthreads();
  for (int off = 1; off < NBMAX; off <<= 1) {
    int v[4];
#pragma unroll
    for (int j = 0; j < 4; ++j) { int i = t + j * 256; v[j] = (i >= off) ? scan[i - off] : 0; }
    __syncthreads();
#pragma unroll
    for (int j = 0; j < 4; ++j) scan[t + j * 256] += v[j];
    __syncthreads();
  }
  // stage into bucket-major LDS order
#pragma unroll
  for (int k = 0; k < EPT; ++k) {
    int i = t + k * 256;
    if (i < valid) {
      int b = (int)myb[k];
      int lpos = (scan[b] - cnt[b]) + (int)(mysl[k] >> 7);
      unsigned src = (unsigned)row[base0 + i];
      staged[lpos] = (src << 7) | (mysl[k] & 127u);
      sbid[lpos] = (unsigned short)b;
    }
  }
  __syncthreads();
  // reserve global ranges; cnt[b] <- gdelta = gbase - lbase
#pragma unroll
  for (int j = 0; j < 4; ++j) {
    int b = t + j * 256;
    int c = cnt[b];
    if (c > 0) {
      int lbase = scan[b] - c;
      int gbase = atomicAdd(&gcur[b], c);
      cnt[b] = gbase - lbase;
    }
  }
  __syncthreads();
  // burst write: consecutive lpos in a bucket -> consecutive global pos
  for (int i = t; i < valid; i += 256) {
    pairs[cnt[sbid[i]] + i] = staged[i];
  }
}

// ---- h = x @ W (fp32 compute), store h as bf16 [node][128] ----
__global__ __launch_bounds__(256) void k_gemm(const float* __restrict__ x,
                                              const float* __restrict__ Wm,
                                              unsigned short* __restrict__ hb, int n) {
  __shared__ float xs[BM * F];   // 32 KB
  int t = threadIdx.x;
  int row0 = blockIdx.x * BM;
  int rows = n - row0; if (rows > BM) rows = BM;
  {
    const float4* x4 = (const float4*)(x + (size_t)row0 * F);
    float4* xs4 = (float4*)xs;
    for (int i = t; i < rows * (F / 4); i += 256) xs4[i] = x4[i];
  }
  __syncthreads();

  int c0 = (t & 31) * 4;
  int r0 = (t >> 5) * 8;
  float acc[8][4] = {{0.f}};
#pragma unroll 2
  for (int k = 0; k < F; k += 4) {
    float4 wv[4];
#pragma unroll
    for (int kk = 0; kk < 4; ++kk) wv[kk] = *(const float4*)&Wm[(size_t)(k + kk) * F + c0];
#pragma unroll
    for (int r = 0; r < 8; ++r) {
      float4 xv = *(const float4*)&xs[(r0 + r) * F + k];
      acc[r][0] = fmaf(xv.x, wv[0].x, acc[r][0]);
      acc[r][1] = fmaf(xv.x, wv[0].y, acc[r][1]);
      acc[r][2] = fmaf(xv.x, wv[0].z, acc[r][2]);
      acc[r][3] = fmaf(xv.x, wv[0].w, acc[r][3]);
      acc[r][0] = fmaf(xv.y, wv[1].x, acc[r][0]);
      acc[r][1] = fmaf(xv.y, wv[1].y, acc[r][1]);
      acc[r][2] = fmaf(xv.y, wv[1].z, acc[r][2]);
      acc[r][3] = fmaf(xv.y, wv[1].w, acc[r][3]);
      acc[r][0] = fmaf(xv.z, wv[2].x, acc[r][0]);
      acc[r][1] = fmaf(xv.z, wv[2].y, acc[r][1]);
      acc[r][2] = fmaf(xv.z, wv[2].z, acc[r][2]);
      acc[r][3] = fmaf(xv.z, wv[2].w, acc[r][3]);
      acc[r][0] = fmaf(xv.w, wv[3].x, acc[r][0]);
      acc[r][1] = fmaf(xv.w, wv[3].y, acc[r][1]);
      acc[r][2] = fmaf(xv.w, wv[3].z, acc[r][2]);
      acc[r][3] = fmaf(xv.w, wv[3].w, acc[r][3]);
    }
  }
#pragma unroll
  for (int r = 0; r < 8; ++r) {
    int gr = row0 + r0 + r;
    if (gr < n) {
      unsigned p0 = (unsigned)f2bf(acc[r][0]) | ((unsigned)f2bf(acc[r][1]) << 16);
      unsigned p1 = (unsigned)f2bf(acc[r][2]) | ((unsigned)f2bf(acc[r][3]) << 16);
      uint2 pv; pv.x = p0; pv.y = p1;
      *(uint2*)&hb[(size_t)gr * F + c0] = pv;
    }
  }
}

// ---- bucketed gather: one block per 128-node bucket, LDS out-tile ----
// tile = bias + d2*h_self + sum_edges w*h[src]; fused BN partial stats.
__global__ __launch_bounds__(256) void k_gather(const int* __restrict__ bucketBase,
                                                const unsigned* __restrict__ pairs,
                                                const float* __restrict__ dinv,
                                                const unsigned short* __restrict__ hb,
                                                const float* __restrict__ bias,
                                                float* __restrict__ out,
                                                float* __restrict__ stats, int n) {
  __shared__ float tile[128][128];  // 64 KB exactly
  int bkt = blockIdx.x;
  int node0 = bkt << 7;
  int nodes = n - node0; if (nodes > 128) nodes = 128;
  int t = threadIdx.x;
  // init tile with bias + self-loop
  for (int idx = t; idx < nodes * 64; idx += 256) {
    int ni = idx >> 6; int p = idx & 63;
    float dv = dinv[node0 + ni]; float d2 = dv * dv;
    unsigned hw = ((const unsigned*)hb)[(size_t)(node0 + ni) * 64 + p];
    float lo = __uint_as_float(hw << 16);
    float hi = __uint_as_float(hw & 0xffff0000u);
    tile[ni][2 * p]     = bias[2 * p]     + lo * d2;
    tile[ni][2 * p + 1] = bias[2 * p + 1] + hi * d2;
  }
  __syncthreads();

  int ebeg = bucketBase[bkt], eend = bucketBase[bkt + 1];
  int lane = t & 63, w = t >> 6;
  for (int i0 = ebeg + w * 64; i0 < eend; i0 += 256) {
    unsigned pk = 0; float wgt = 0.f;
    if (i0 + lane < eend) {
      pk = pairs[i0 + lane];
      int s = (int)(pk >> 7), nl = (int)(pk & 127u);
      wgt = dinv[s] * dinv[node0 + nl];
    }
    int m = eend - i0; if (m > 64) m = 64;
    for (int j = 0; j < m; ++j) {
      unsigned pj = __shfl(pk, j);
      float wj = __shfl(wgt, j);
      int s = (int)(pj >> 7), nl = (int)(pj & 127u);
      const unsigned short* hp = hb + (size_t)s * F;
      float v0 = __uint_as_float(((unsigned)hp[lane]) << 16);
      float v1 = __uint_as_float(((unsigned)hp[lane + 64]) << 16);
      atomicAdd(&tile[nl][lane],      v0 * wj);   // bank-stride 1: conflict-free
      atomicAdd(&tile[nl][lane + 64], v1 * wj);
    }
  }
  __syncthreads();
  // write out
  for (int idx = t; idx < nodes * F; idx += 256) {
    int ni = idx >> 7, f = idx & 127;
    out[(size_t)(node0 + ni) * F + f] = tile[ni][f];
  }
  // fused BN partial stats
  float s = 0.f, ss = 0.f;
  int f = t & 127, half = t >> 7;
  for (int ni = half; ni < nodes; ni += 2) {
    float v = tile[ni][f];
    s += v; ss += v * v;
  }
  __syncthreads();
  float* sh = &tile[0][0];  // reuse tile as scratch
  sh[t] = s; sh[256 + t] = ss;
  __syncthreads();
  if (t < 128) {
    atomicAdd(&stats[t],     sh[t]       + sh[t + 128]);
    atomicAdd(&stats[F + t], sh[256 + t] + sh[256 + t + 128]);
  }
}

// ---- finalize scale/shift ----
__global__ void k_fin(float* __restrict__ stats, const float* __restrict__ gamma,
                      const float* __restrict__ beta, int n) {
  int f = threadIdx.x;
  if (f >= F) return;
  float inv_n = 1.0f / (float)n;
  float mean = stats[f] * inv_n;
  float var = stats[F + f] * inv_n - mean * mean;
  float scale = gamma[f] * rsqrtf(var + EPSV);
  stats[2 * F + f] = scale;
  stats[3 * F + f] = beta[f] - mean * scale;
}

// ---- apply BN + ReLU in place ----
__global__ __launch_bounds__(256) void k_apply(float* __restrict__ out,
                                               const float* __restrict__ stats, int n) {
  long long i4 = (long long)blockIdx.x * 256 + threadIdx.x;
  if (i4 >= (long long)n * (F / 4)) return;
  int c0 = ((int)i4 & 31) * 4;
  float4 v = *(const float4*)(out + i4 * 4);
  float4 sc = *(const float4*)(stats + 2 * F + c0);
  float4 sf = *(const float4*)(stats + 3 * F + c0);
  float4 o;
  o.x = fmaxf(v.x * sc.x + sf.x, 0.f);
  o.y = fmaxf(v.y * sc.y + sf.y, 0.f);
  o.z = fmaxf(v.z * sc.z + sf.z, 0.f);
  o.w = fmaxf(v.w * sc.w + sf.w, 0.f);
  *(float4*)(out + i4 * 4) = o;
}

extern "C" void kernel_launch(void* const* d_in, const int* in_sizes, int n_in,
                              void* d_out, int out_size, void* d_ws, size_t ws_size,
                              hipStream_t stream) {
  const float* x     = (const float*)d_in[0];
  const int*   ei    = (const int*)d_in[1];
  const float* W     = (const float*)d_in[2];
  const float* b     = (const float*)d_in[3];
  const float* gamma = (const float*)d_in[4];
  const float* beta  = (const float*)d_in[5];
  int n = in_sizes[0] / F;
  int e = in_sizes[1] / 2;
  const int* row = ei;       // sources
  const int* col = ei + e;   // targets

  float* out = (float*)d_out;
  int nb = (n + 127) >> 7;

  // workspace layout
  char* wp = (char*)d_ws;
  unsigned short* hb = (unsigned short*)wp;            wp += (size_t)n * F * 2;
  float* dinv        = (float*)wp;                     wp += (size_t)n * 4;
  float* stats       = (float*)wp;                     wp += 512 * 4;
  int* deg           = (int*)wp;                       wp += (size_t)n * 4;
  int* bucketCnt     = (int*)wp;                       wp += NBMAX * 4;
  int* bucketBase    = (int*)wp;                       wp += (NBMAX + 1) * 4;
  int* gcur          = (int*)wp;                       wp += NBMAX * 4;
  unsigned* pairs    = (unsigned*)wp;                  wp += (size_t)e * 4;

  k_zero   <<<(n + 255) / 256, 256, 0, stream>>>(deg, bucketCnt, stats, n);
  k_degc   <<<(e + 255) / 256, 256, 0, stream>>>(col, deg, e);
  k_bsum   <<<nb, 128, 0, stream>>>(deg, bucketCnt, dinv, n);
  k_bscan  <<<1, 256, 0, stream>>>(bucketCnt, bucketBase, gcur, e, nb);
  k_binfill<<<(e + CHUNK - 1) / CHUNK, 256, 0, stream>>>(row, col, gcur, pairs, e);
  k_gemm   <<<(n + BM - 1) / BM, 256, 0, stream>>>(x, W, hb, n);
  k_gather <<<nb, 256, 0, stream>>>(bucketBase, pairs, dinv, hb, b, out, stats, n);
  k_fin    <<<1, F, 0, stream>>>(stats, gamma, beta, n);
  k_apply  <<<(int)(((long long)n * (F / 4) + 255) / 256), 256, 0, stream>>>(out, stats, n);
}

// Round 5
// 293.043 us; speedup vs baseline: 5.3966x; 5.3966x over previous
//
#include <hip/hip_runtime.h>
#include <cstddef>

#define F 128
#define BM 64
#define EPSV 1e-5f
#define NBMAX 1024   // padded bucket count; NB = ceil(n/128)
#define CHUNK 8192   // edges per binfill block
#define EPT 32       // edges per thread in binfill (CHUNK/256)

__device__ inline unsigned short f2bf(float v) {  // RNE f32->bf16
  unsigned u = __float_as_uint(v);
  return (unsigned short)((u + 0x7fffu + ((u >> 16) & 1u)) >> 16);
}
__device__ inline float bf_lo(unsigned u) { return __uint_as_float(u << 16); }
__device__ inline float bf_hi(unsigned u) { return __uint_as_float(u & 0xffff0000u); }

// ---- zero deg, bucketCnt, BN stat accumulators ----
__global__ __launch_bounds__(256) void k_zero(int* __restrict__ deg,
                                              int* __restrict__ bucketCnt,
                                              float* __restrict__ stats, int n) {
  int i = blockIdx.x * 256 + threadIdx.x;
  if (i < n) deg[i] = 0;
  if (i < NBMAX) bucketCnt[i] = 0;
  if (i < 256) stats[i] = 0.0f;
}

// ---- in-degree count over edge targets ----
__global__ __launch_bounds__(256) void k_degc(const int* __restrict__ col,
                                              int* __restrict__ deg, int e) {
  int i = blockIdx.x * 256 + threadIdx.x;
  if (i < e) atomicAdd(&deg[col[i]], 1);
}

// ---- per-bucket degree sums (128 nodes/bucket) + dinv = rsqrt(1+deg) ----
__global__ __launch_bounds__(128) void k_bsum(const int* __restrict__ deg,
                                              int* __restrict__ bucketCnt,
                                              float* __restrict__ dinv, int n) {
  __shared__ int sb[128];
  int t = threadIdx.x;
  int gid = blockIdx.x * 128 + t;
  int d = (gid < n) ? deg[gid] : 0;
  if (gid < n) dinv[gid] = rsqrtf((float)(1 + d));
  sb[t] = d;
  __syncthreads();
  for (int off = 64; off > 0; off >>= 1) {
    if (t < off) sb[t] += sb[t + off];
    __syncthreads();
  }
  if (t == 0) bucketCnt[blockIdx.x] = sb[0];
}

// ---- single-block scan of bucketCnt -> bucketBase (exclusive) + cursor ----
__global__ __launch_bounds__(256) void k_bscan(const int* __restrict__ bucketCnt,
                                               int* __restrict__ bucketBase,
                                               int* __restrict__ gcur,
                                               int* __restrict__ rowptr,
                                               int e, int nb, int n) {
  __shared__ int sc[NBMAX];
  int t = threadIdx.x;
#pragma unroll
  for (int j = 0; j < 4; ++j) sc[t + j * 256] = bucketCnt[t + j * 256];
  __syncthreads();
  for (int off = 1; off < NBMAX; off <<= 1) {
    int v[4];
#pragma unroll
    for (int j = 0; j < 4; ++j) { int i = t + j * 256; v[j] = (i >= off) ? sc[i - off] : 0; }
    __syncthreads();
#pragma unroll
    for (int j = 0; j < 4; ++j) sc[t + j * 256] += v[j];
    __syncthreads();
  }
#pragma unroll
  for (int j = 0; j < 4; ++j) {
    int i = t + j * 256;
    int ex = sc[i] - bucketCnt[i];
    bucketBase[i] = ex;
    gcur[i] = ex;
  }
  if (t == 0) { bucketBase[nb] = e; rowptr[n] = e; }
}

// ---- LDS-staged multi-split: bin edges by target bucket, burst writes ----
// pairs[pos] = (src << 7) | (col & 127), grouped by bucket (order arbitrary)
__global__ __launch_bounds__(256) void k_binfill(const int* __restrict__ row,
                                                 const int* __restrict__ col,
                                                 int* __restrict__ gcur,
                                                 unsigned* __restrict__ pairs, int e) {
  __shared__ unsigned staged[CHUNK];        // 32 KB
  __shared__ unsigned short sbid[CHUNK];    // 16 KB
  __shared__ int cnt[NBMAX];                // 4 KB
  __shared__ int scan[NBMAX];               // 4 KB
  int t = threadIdx.x;
  int base0 = blockIdx.x * CHUNK;
  int valid = e - base0; if (valid > CHUNK) valid = CHUNK;
#pragma unroll
  for (int j = 0; j < 4; ++j) cnt[t + j * 256] = 0;
  __syncthreads();
  unsigned myb[EPT];   // bucket id
  unsigned mysl[EPT];  // (seq << 7) | colLow
#pragma unroll
  for (int k = 0; k < EPT; ++k) {
    int i = t + k * 256;
    if (i < valid) {
      int c = col[base0 + i];
      int b = c >> 7;
      int seq = atomicAdd(&cnt[b], 1);
      myb[k] = (unsigned)b;
      mysl[k] = ((unsigned)seq << 7) | (unsigned)(c & 127);
    }
  }
  __syncthreads();
#pragma unroll
  for (int j = 0; j < 4; ++j) scan[t + j * 256] = cnt[t + j * 256];
  __syncthreads();
  for (int off = 1; off < NBMAX; off <<= 1) {
    int v[4];
#pragma unroll
    for (int j = 0; j < 4; ++j) { int i = t + j * 256; v[j] = (i >= off) ? scan[i - off] : 0; }
    __syncthreads();
#pragma unroll
    for (int j = 0; j < 4; ++j) scan[t + j * 256] += v[j];
    __syncthreads();
  }
  // stage into bucket-major LDS order
#pragma unroll
  for (int k = 0; k < EPT; ++k) {
    int i = t + k * 256;
    if (i < valid) {
      int b = (int)myb[k];
      int lpos = (scan[b] - cnt[b]) + (int)(mysl[k] >> 7);
      unsigned src = (unsigned)row[base0 + i];
      staged[lpos] = (src << 7) | (mysl[k] & 127u);
      sbid[lpos] = (unsigned short)b;
    }
  }
  __syncthreads();
  // reserve global ranges; cnt[b] <- gdelta = gbase - lbase
#pragma unroll
  for (int j = 0; j < 4; ++j) {
    int b = t + j * 256;
    int c = cnt[b];
    if (c > 0) {
      int lbase = scan[b] - c;
      int gbase = atomicAdd(&gcur[b], c);
      cnt[b] = gbase - lbase;
    }
  }
  __syncthreads();
  // burst write: consecutive lpos in a bucket -> consecutive global pos
  for (int i = t; i < valid; i += 256) {
    pairs[cnt[sbid[i]] + i] = staged[i];
  }
}

// ---- bucket-local counting sort: pairs (bucket-major) -> srcs (node-major CSR) ----
// Random writes stay inside this bucket's ~8KB window -> no cross-L2 write
// amplification (the R3 k_fill failure mode). Also emits rowptr.
__global__ __launch_bounds__(256) void k_sort2(const int* __restrict__ bucketBase,
                                               const unsigned* __restrict__ pairs,
                                               const int* __restrict__ deg,
                                               int* __restrict__ rowptr,
                                               int* __restrict__ srcs, int n) {
  __shared__ int sd[128];
  __shared__ int cur[128];
  int bkt = blockIdx.x;
  int node0 = bkt << 7;
  int nodes = n - node0; if (nodes > 128) nodes = 128;
  int t = threadIdx.x;
  int ebeg = bucketBase[bkt];
  if (t < 128) sd[t] = (t < nodes) ? deg[node0 + t] : 0;
  __syncthreads();
  for (int off = 1; off < 128; off <<= 1) {
    int v = 0;
    if (t < 128 && t >= off) v = sd[t - off];
    __syncthreads();
    if (t < 128) sd[t] += v;
    __syncthreads();
  }
  if (t < nodes) {
    int base = ebeg + sd[t] - deg[node0 + t];
    rowptr[node0 + t] = base;
    cur[t] = base;
  }
  __syncthreads();
  int eend = bucketBase[bkt + 1];
  for (int i = ebeg + t; i < eend; i += 256) {
    unsigned pk = pairs[i];
    int pos = atomicAdd(&cur[pk & 127u], 1);
    srcs[pos] = (int)(pk >> 7);
  }
}

// ---- h = x @ W (fp32 compute), store h as bf16 [node][128] ----
__global__ __launch_bounds__(256) void k_gemm(const float* __restrict__ x,
                                              const float* __restrict__ Wm,
                                              unsigned short* __restrict__ hb, int n) {
  __shared__ float xs[BM * F];   // 32 KB
  int t = threadIdx.x;
  int row0 = blockIdx.x * BM;
  int rows = n - row0; if (rows > BM) rows = BM;
  {
    const float4* x4 = (const float4*)(x + (size_t)row0 * F);
    float4* xs4 = (float4*)xs;
    for (int i = t; i < rows * (F / 4); i += 256) xs4[i] = x4[i];
  }
  __syncthreads();

  int c0 = (t & 31) * 4;
  int r0 = (t >> 5) * 8;
  float acc[8][4] = {{0.f}};
#pragma unroll 2
  for (int k = 0; k < F; k += 4) {
    float4 wv[4];
#pragma unroll
    for (int kk = 0; kk < 4; ++kk) wv[kk] = *(const float4*)&Wm[(size_t)(k + kk) * F + c0];
#pragma unroll
    for (int r = 0; r < 8; ++r) {
      float4 xv = *(const float4*)&xs[(r0 + r) * F + k];
      acc[r][0] = fmaf(xv.x, wv[0].x, acc[r][0]);
      acc[r][1] = fmaf(xv.x, wv[0].y, acc[r][1]);
      acc[r][2] = fmaf(xv.x, wv[0].z, acc[r][2]);
      acc[r][3] = fmaf(xv.x, wv[0].w, acc[r][3]);
      acc[r][0] = fmaf(xv.y, wv[1].x, acc[r][0]);
      acc[r][1] = fmaf(xv.y, wv[1].y, acc[r][1]);
      acc[r][2] = fmaf(xv.y, wv[1].z, acc[r][2]);
      acc[r][3] = fmaf(xv.y, wv[1].w, acc[r][3]);
      acc[r][0] = fmaf(xv.z, wv[2].x, acc[r][0]);
      acc[r][1] = fmaf(xv.z, wv[2].y, acc[r][1]);
      acc[r][2] = fmaf(xv.z, wv[2].z, acc[r][2]);
      acc[r][3] = fmaf(xv.z, wv[2].w, acc[r][3]);
      acc[r][0] = fmaf(xv.w, wv[3].x, acc[r][0]);
      acc[r][1] = fmaf(xv.w, wv[3].y, acc[r][1]);
      acc[r][2] = fmaf(xv.w, wv[3].z, acc[r][2]);
      acc[r][3] = fmaf(xv.w, wv[3].w, acc[r][3]);
    }
  }
#pragma unroll
  for (int r = 0; r < 8; ++r) {
    int gr = row0 + r0 + r;
    if (gr < n) {
      unsigned p0 = (unsigned)f2bf(acc[r][0]) | ((unsigned)f2bf(acc[r][1]) << 16);
      unsigned p1 = (unsigned)f2bf(acc[r][2]) | ((unsigned)f2bf(acc[r][3]) << 16);
      uint2 pv; pv.x = p0; pv.y = p1;
      *(uint2*)&hb[(size_t)gr * F + c0] = pv;
    }
  }
}

// ---- CSR gather: one wave per node, bf16 h, 4-edge MLP batching ----
__global__ __launch_bounds__(256) void k_gather(const int* __restrict__ rowptr,
                                                const int* __restrict__ srcs,
                                                const float* __restrict__ dinv,
                                                const unsigned* __restrict__ hb32,
                                                const float* __restrict__ bias,
                                                float* __restrict__ out, int n) {
  int node = blockIdx.x * 4 + (threadIdx.x >> 6);
  if (node >= n) return;
  int lane = threadIdx.x & 63;
  float dc = dinv[node];
  int beg = rowptr[node], end = rowptr[node + 1];

  unsigned hw = hb32[(size_t)node * 64 + lane];  // feats 2*lane, 2*lane+1
  float2 bv = *(const float2*)&bias[lane * 2];
  float d2 = dc * dc;
  float ax = bv.x + bf_lo(hw) * d2;
  float ay = bv.y + bf_hi(hw) * d2;

  for (int chunk = beg; chunk < end; chunk += 64) {
    int m = end - chunk; if (m > 64) m = 64;
    int myidx = 0; float myw = 0.f;
    if (chunk + lane < end) {
      myidx = srcs[chunk + lane];
      myw = dinv[myidx] * dc;
    }
    int j = 0;
    for (; j + 4 <= m; j += 4) {
      int s0 = __shfl(myidx, j),     s1 = __shfl(myidx, j + 1);
      int s2 = __shfl(myidx, j + 2), s3 = __shfl(myidx, j + 3);
      float w0 = __shfl(myw, j),     w1 = __shfl(myw, j + 1);
      float w2 = __shfl(myw, j + 2), w3 = __shfl(myw, j + 3);
      unsigned a0 = hb32[(size_t)s0 * 64 + lane];   // 4 independent loads in flight
      unsigned a1 = hb32[(size_t)s1 * 64 + lane];
      unsigned a2 = hb32[(size_t)s2 * 64 + lane];
      unsigned a3 = hb32[(size_t)s3 * 64 + lane];
      ax = fmaf(bf_lo(a0), w0, ax); ay = fmaf(bf_hi(a0), w0, ay);
      ax = fmaf(bf_lo(a1), w1, ax); ay = fmaf(bf_hi(a1), w1, ay);
      ax = fmaf(bf_lo(a2), w2, ax); ay = fmaf(bf_hi(a2), w2, ay);
      ax = fmaf(bf_lo(a3), w3, ax); ay = fmaf(bf_hi(a3), w3, ay);
    }
    for (; j < m; ++j) {
      int s0 = __shfl(myidx, j);
      float w0 = __shfl(myw, j);
      unsigned a0 = hb32[(size_t)s0 * 64 + lane];
      ax = fmaf(bf_lo(a0), w0, ax); ay = fmaf(bf_hi(a0), w0, ay);
    }
  }
  float2 o; o.x = ax; o.y = ay;
  *(float2*)&out[(size_t)node * F + lane * 2] = o;
}

// ---- BN partial stats: per-feature sum / sumsq ----
__global__ __launch_bounds__(256) void k_stats(const float* __restrict__ out,
                                               float* __restrict__ stats, int n) {
  int f = threadIdx.x & (F - 1);
  int half = threadIdx.x >> 7;
  int rpb = (n + gridDim.x - 1) / gridDim.x;
  int r0 = blockIdx.x * rpb;
  int r1 = r0 + rpb; if (r1 > n) r1 = n;
  float s = 0.f, ss = 0.f;
  for (int r = r0 + half; r < r1; r += 2) {
    float v = out[(size_t)r * F + f];
    s += v; ss += v * v;
  }
  __shared__ float sh[2][F][2];
  sh[0][f][half] = s; sh[1][f][half] = ss;
  __syncthreads();
  if (half == 0) {
    atomicAdd(&stats[f], sh[0][f][0] + sh[0][f][1]);
    atomicAdd(&stats[F + f], sh[1][f][0] + sh[1][f][1]);
  }
}

// ---- finalize scale/shift ----
__global__ void k_fin(float* __restrict__ stats, const float* __restrict__ gamma,
                      const float* __restrict__ beta, int n) {
  int f = threadIdx.x;
  if (f >= F) return;
  float inv_n = 1.0f / (float)n;
  float mean = stats[f] * inv_n;
  float var = stats[F + f] * inv_n - mean * mean;
  float scale = gamma[f] * rsqrtf(var + EPSV);
  stats[2 * F + f] = scale;
  stats[3 * F + f] = beta[f] - mean * scale;
}

// ---- apply BN + ReLU in place ----
__global__ __launch_bounds__(256) void k_apply(float* __restrict__ out,
                                               const float* __restrict__ stats, int n) {
  long long i4 = (long long)blockIdx.x * 256 + threadIdx.x;
  if (i4 >= (long long)n * (F / 4)) return;
  int c0 = ((int)i4 & 31) * 4;
  float4 v = *(const float4*)(out + i4 * 4);
  float4 sc = *(const float4*)(stats + 2 * F + c0);
  float4 sf = *(const float4*)(stats + 3 * F + c0);
  float4 o;
  o.x = fmaxf(v.x * sc.x + sf.x, 0.f);
  o.y = fmaxf(v.y * sc.y + sf.y, 0.f);
  o.z = fmaxf(v.z * sc.z + sf.z, 0.f);
  o.w = fmaxf(v.w * sc.w + sf.w, 0.f);
  *(float4*)(out + i4 * 4) = o;
}

extern "C" void kernel_launch(void* const* d_in, const int* in_sizes, int n_in,
                              void* d_out, int out_size, void* d_ws, size_t ws_size,
                              hipStream_t stream) {
  const float* x     = (const float*)d_in[0];
  const int*   ei    = (const int*)d_in[1];
  const float* W     = (const float*)d_in[2];
  const float* b     = (const float*)d_in[3];
  const float* gamma = (const float*)d_in[4];
  const float* beta  = (const float*)d_in[5];
  int n = in_sizes[0] / F;
  int e = in_sizes[1] / 2;
  const int* row = ei;       // sources
  const int* col = ei + e;   // targets

  float* out = (float*)d_out;
  int nb = (n + 127) >> 7;

  // workspace layout
  char* wp = (char*)d_ws;
  unsigned short* hb = (unsigned short*)wp;            wp += (size_t)n * F * 2;
  float* dinv        = (float*)wp;                     wp += (size_t)n * 4;
  float* stats       = (float*)wp;                     wp += 512 * 4;
  int* deg           = (int*)wp;                       wp += (size_t)n * 4;
  int* bucketCnt     = (int*)wp;                       wp += NBMAX * 4;
  int* bucketBase    = (int*)wp;                       wp += (NBMAX + 1) * 4;
  int* gcur          = (int*)wp;                       wp += NBMAX * 4;
  int* rowptr        = (int*)wp;                       wp += (size_t)(n + 1) * 4;
  unsigned* pairs    = (unsigned*)wp;                  wp += (size_t)e * 4;
  int* srcs          = (int*)wp;                       wp += (size_t)e * 4;

  k_zero   <<<(n + 255) / 256, 256, 0, stream>>>(deg, bucketCnt, stats, n);
  k_degc   <<<(e + 255) / 256, 256, 0, stream>>>(col, deg, e);
  k_bsum   <<<nb, 128, 0, stream>>>(deg, bucketCnt, dinv, n);
  k_bscan  <<<1, 256, 0, stream>>>(bucketCnt, bucketBase, gcur, rowptr, e, nb, n);
  k_binfill<<<(e + CHUNK - 1) / CHUNK, 256, 0, stream>>>(row, col, gcur, pairs, e);
  k_sort2  <<<nb, 256, 0, stream>>>(bucketBase, pairs, deg, rowptr, srcs, n);
  k_gemm   <<<(n + BM - 1) / BM, 256, 0, stream>>>(x, W, hb, n);
  k_gather <<<(n + 3) / 4, 256, 0, stream>>>(rowptr, srcs, dinv, (const unsigned*)hb, b, out, n);
  k_stats  <<<512, 256, 0, stream>>>(out, stats, n);
  k_fin    <<<1, F, 0, stream>>>(stats, gamma, beta, n);
  k_apply  <<<(int)(((long long)n * (F / 4) + 255) / 256), 256, 0, stream>>>(out, stats, n);
}

// Round 6
// 278.652 us; speedup vs baseline: 5.6753x; 1.0516x over previous
//
#include <hip/hip_runtime.h>
#include <cstddef>

#define F 128
#define EPSV 1e-5f
#define NBMAX 1024   // padded bucket count; NB = ceil(n/128)
#define CHUNK 8192   // edges per binfill block
#define EPT 32       // edges per thread in binfill (CHUNK/256)

typedef short bf16x8 __attribute__((ext_vector_type(8)));
typedef float f32x4 __attribute__((ext_vector_type(4)));

__device__ inline unsigned short f2bf(float v) {  // RNE f32->bf16
  unsigned u = __float_as_uint(v);
  return (unsigned short)((u + 0x7fffu + ((u >> 16) & 1u)) >> 16);
}
__device__ inline float bf_lo(unsigned u) { return __uint_as_float(u << 16); }
__device__ inline float bf_hi(unsigned u) { return __uint_as_float(u & 0xffff0000u); }

// ---- zero deg, bucketCnt, BN stat accumulators ----
__global__ __launch_bounds__(256) void k_zero(int* __restrict__ deg,
                                              int* __restrict__ bucketCnt,
                                              float* __restrict__ stats, int n) {
  int i = blockIdx.x * 256 + threadIdx.x;
  if (i < n) deg[i] = 0;
  if (i < NBMAX) bucketCnt[i] = 0;
  if (i < 256) stats[i] = 0.0f;
}

// ---- in-degree count over edge targets ----
__global__ __launch_bounds__(256) void k_degc(const int* __restrict__ col,
                                              int* __restrict__ deg, int e) {
  int i = blockIdx.x * 256 + threadIdx.x;
  if (i < e) atomicAdd(&deg[col[i]], 1);
}

// ---- per-bucket degree sums (128 nodes/bucket) + dinv = rsqrt(1+deg) ----
__global__ __launch_bounds__(128) void k_bsum(const int* __restrict__ deg,
                                              int* __restrict__ bucketCnt,
                                              float* __restrict__ dinv, int n) {
  __shared__ int sb[128];
  int t = threadIdx.x;
  int gid = blockIdx.x * 128 + t;
  int d = (gid < n) ? deg[gid] : 0;
  if (gid < n) dinv[gid] = rsqrtf((float)(1 + d));
  sb[t] = d;
  __syncthreads();
  for (int off = 64; off > 0; off >>= 1) {
    if (t < off) sb[t] += sb[t + off];
    __syncthreads();
  }
  if (t == 0) bucketCnt[blockIdx.x] = sb[0];
}

// ---- single-block scan of bucketCnt -> bucketBase (exclusive) + cursor ----
__global__ __launch_bounds__(256) void k_bscan(const int* __restrict__ bucketCnt,
                                               int* __restrict__ bucketBase,
                                               int* __restrict__ gcur,
                                               int* __restrict__ rowptr,
                                               int e, int nb, int n) {
  __shared__ int sc[NBMAX];
  int t = threadIdx.x;
#pragma unroll
  for (int j = 0; j < 4; ++j) sc[t + j * 256] = bucketCnt[t + j * 256];
  __syncthreads();
  for (int off = 1; off < NBMAX; off <<= 1) {
    int v[4];
#pragma unroll
    for (int j = 0; j < 4; ++j) { int i = t + j * 256; v[j] = (i >= off) ? sc[i - off] : 0; }
    __syncthreads();
#pragma unroll
    for (int j = 0; j < 4; ++j) sc[t + j * 256] += v[j];
    __syncthreads();
  }
#pragma unroll
  for (int j = 0; j < 4; ++j) {
    int i = t + j * 256;
    int ex = sc[i] - bucketCnt[i];
    bucketBase[i] = ex;
    gcur[i] = ex;
  }
  if (t == 0) { bucketBase[nb] = e; rowptr[n] = e; }
}

// ---- LDS-staged multi-split: bin edges by target bucket, burst writes ----
__global__ __launch_bounds__(256) void k_binfill(const int* __restrict__ row,
                                                 const int* __restrict__ col,
                                                 int* __restrict__ gcur,
                                                 unsigned* __restrict__ pairs, int e) {
  __shared__ unsigned staged[CHUNK];        // 32 KB
  __shared__ unsigned short sbid[CHUNK];    // 16 KB
  __shared__ int cnt[NBMAX];                // 4 KB
  __shared__ int scan[NBMAX];               // 4 KB
  int t = threadIdx.x;
  int base0 = blockIdx.x * CHUNK;
  int valid = e - base0; if (valid > CHUNK) valid = CHUNK;
#pragma unroll
  for (int j = 0; j < 4; ++j) cnt[t + j * 256] = 0;
  __syncthreads();
  unsigned myb[EPT];
  unsigned mysl[EPT];
#pragma unroll
  for (int k = 0; k < EPT; ++k) {
    int i = t + k * 256;
    if (i < valid) {
      int c = col[base0 + i];
      int b = c >> 7;
      int seq = atomicAdd(&cnt[b], 1);
      myb[k] = (unsigned)b;
      mysl[k] = ((unsigned)seq << 7) | (unsigned)(c & 127);
    }
  }
  __syncthreads();
#pragma unroll
  for (int j = 0; j < 4; ++j) scan[t + j * 256] = cnt[t + j * 256];
  __syncthreads();
  for (int off = 1; off < NBMAX; off <<= 1) {
    int v[4];
#pragma unroll
    for (int j = 0; j < 4; ++j) { int i = t + j * 256; v[j] = (i >= off) ? scan[i - off] : 0; }
    __syncthreads();
#pragma unroll
    for (int j = 0; j < 4; ++j) scan[t + j * 256] += v[j];
    __syncthreads();
  }
#pragma unroll
  for (int k = 0; k < EPT; ++k) {
    int i = t + k * 256;
    if (i < valid) {
      int b = (int)myb[k];
      int lpos = (scan[b] - cnt[b]) + (int)(mysl[k] >> 7);
      unsigned src = (unsigned)row[base0 + i];
      staged[lpos] = (src << 7) | (mysl[k] & 127u);
      sbid[lpos] = (unsigned short)b;
    }
  }
  __syncthreads();
#pragma unroll
  for (int j = 0; j < 4; ++j) {
    int b = t + j * 256;
    int c = cnt[b];
    if (c > 0) {
      int lbase = scan[b] - c;
      int gbase = atomicAdd(&gcur[b], c);
      cnt[b] = gbase - lbase;
    }
  }
  __syncthreads();
  for (int i = t; i < valid; i += 256) {
    pairs[cnt[sbid[i]] + i] = staged[i];
  }
}

// ---- bucket-local counting sort: pairs -> srcs (node-major CSR) + rowptr ----
__global__ __launch_bounds__(256) void k_sort2(const int* __restrict__ bucketBase,
                                               const unsigned* __restrict__ pairs,
                                               const int* __restrict__ deg,
                                               int* __restrict__ rowptr,
                                               int* __restrict__ srcs, int n) {
  __shared__ int sd[128];
  __shared__ int cur[128];
  int bkt = blockIdx.x;
  int node0 = bkt << 7;
  int nodes = n - node0; if (nodes > 128) nodes = 128;
  int t = threadIdx.x;
  int ebeg = bucketBase[bkt];
  if (t < 128) sd[t] = (t < nodes) ? deg[node0 + t] : 0;
  __syncthreads();
  for (int off = 1; off < 128; off <<= 1) {
    int v = 0;
    if (t < 128 && t >= off) v = sd[t - off];
    __syncthreads();
    if (t < 128) sd[t] += v;
    __syncthreads();
  }
  if (t < nodes) {
    int base = ebeg + sd[t] - deg[node0 + t];
    rowptr[node0 + t] = base;
    cur[t] = base;
  }
  __syncthreads();
  int eend = bucketBase[bkt + 1];
  for (int i = ebeg + t; i < eend; i += 256) {
    unsigned pk = pairs[i];
    int pos = atomicAdd(&cur[pk & 127u], 1);
    srcs[pos] = (int)(pk >> 7);
  }
}

// ---- W (f32 row-major) -> Wt (bf16 col-major: wt[c*128+k]) ----
__global__ __launch_bounds__(256) void k_wconv(const float* __restrict__ Wm,
                                               unsigned short* __restrict__ wt) {
  int idx = blockIdx.x * 256 + threadIdx.x;
  if (idx < F * F) {
    int k = idx >> 7, c = idx & 127;
    wt[c * F + k] = f2bf(Wm[idx]);
  }
}

// ---- h = x @ W via MFMA bf16: 4 waves x 16 rows = 64 rows/block ----
// A-frag: row = lane&15, k = (lane>>4)*8 + j (xs padded LDS, ds_read_b128)
// B-frag: col = lane&15, k = (lane>>4)*8 + j (wt col-major, L2-hot global)
// D: col = lane&15, row = (lane>>4)*4 + reg  [m89 layout]
__global__ __launch_bounds__(256) void k_gemm(const float* __restrict__ x,
                                              const unsigned short* __restrict__ wt,
                                              unsigned short* __restrict__ hb, int n) {
  __shared__ unsigned short xs[64 * 136];  // pad 8 bf16 -> 272B row stride
  int t = threadIdx.x;
  int row0 = blockIdx.x * 64;
  {
    int c4 = t & 31;   // float4 index along row
    int rr = t >> 5;   // 0..7
#pragma unroll
    for (int it = 0; it < 8; ++it) {
      int r = rr + it * 8;
      int gr = row0 + r;
      if (gr < n) {
        float4 v = *(const float4*)&x[(size_t)gr * F + c4 * 4];
        unsigned p0 = (unsigned)f2bf(v.x) | ((unsigned)f2bf(v.y) << 16);
        unsigned p1 = (unsigned)f2bf(v.z) | ((unsigned)f2bf(v.w) << 16);
        uint2 pv; pv.x = p0; pv.y = p1;
        *(uint2*)&xs[r * 136 + c4 * 4] = pv;
      }
    }
  }
  __syncthreads();

  int w = t >> 6, l = t & 63;
  int lo = l & 15, hi = l >> 4;  // hi: 0..3
  bf16x8 a[4];
#pragma unroll
  for (int ks = 0; ks < 4; ++ks)
    a[ks] = *(const bf16x8*)&xs[(w * 16 + lo) * 136 + ks * 32 + hi * 8];

  f32x4 acc[8];
#pragma unroll
  for (int ct = 0; ct < 8; ++ct) acc[ct] = (f32x4){0.f, 0.f, 0.f, 0.f};

  const unsigned short* wb = wt + lo * F + hi * 8;
#pragma unroll
  for (int ct = 0; ct < 8; ++ct) {
#pragma unroll
    for (int ks = 0; ks < 4; ++ks) {
      bf16x8 bf = *(const bf16x8*)(wb + ct * 16 * F + ks * 32);
      acc[ct] = __builtin_amdgcn_mfma_f32_16x16x32_bf16(a[ks], bf, acc[ct], 0, 0, 0);
    }
  }

  int node_base = row0 + w * 16 + hi * 4;
#pragma unroll
  for (int ct = 0; ct < 8; ++ct) {
#pragma unroll
    for (int rg = 0; rg < 4; ++rg) {
      int node = node_base + rg;
      if (node < n) hb[(size_t)node * F + ct * 16 + lo] = f2bf(acc[ct][rg]);
    }
  }
}

// ---- CSR gather: one wave per node, bf16 h, 4-edge MLP batching ----
__global__ __launch_bounds__(256) void k_gather(const int* __restrict__ rowptr,
                                                const int* __restrict__ srcs,
                                                const float* __restrict__ dinv,
                                                const unsigned* __restrict__ hb32,
                                                const float* __restrict__ bias,
                                                float* __restrict__ out, int n) {
  int node = blockIdx.x * 4 + (threadIdx.x >> 6);
  if (node >= n) return;
  int lane = threadIdx.x & 63;
  float dc = dinv[node];
  int beg = rowptr[node], end = rowptr[node + 1];

  unsigned hw = hb32[(size_t)node * 64 + lane];
  float2 bv = *(const float2*)&bias[lane * 2];
  float d2 = dc * dc;
  float ax = bv.x + bf_lo(hw) * d2;
  float ay = bv.y + bf_hi(hw) * d2;

  for (int chunk = beg; chunk < end; chunk += 64) {
    int m = end - chunk; if (m > 64) m = 64;
    int myidx = 0; float myw = 0.f;
    if (chunk + lane < end) {
      myidx = srcs[chunk + lane];
      myw = dinv[myidx] * dc;
    }
    int j = 0;
    for (; j + 4 <= m; j += 4) {
      int s0 = __shfl(myidx, j),     s1 = __shfl(myidx, j + 1);
      int s2 = __shfl(myidx, j + 2), s3 = __shfl(myidx, j + 3);
      float w0 = __shfl(myw, j),     w1 = __shfl(myw, j + 1);
      float w2 = __shfl(myw, j + 2), w3 = __shfl(myw, j + 3);
      unsigned a0 = hb32[(size_t)s0 * 64 + lane];
      unsigned a1 = hb32[(size_t)s1 * 64 + lane];
      unsigned a2 = hb32[(size_t)s2 * 64 + lane];
      unsigned a3 = hb32[(size_t)s3 * 64 + lane];
      ax = fmaf(bf_lo(a0), w0, ax); ay = fmaf(bf_hi(a0), w0, ay);
      ax = fmaf(bf_lo(a1), w1, ax); ay = fmaf(bf_hi(a1), w1, ay);
      ax = fmaf(bf_lo(a2), w2, ax); ay = fmaf(bf_hi(a2), w2, ay);
      ax = fmaf(bf_lo(a3), w3, ax); ay = fmaf(bf_hi(a3), w3, ay);
    }
    for (; j < m; ++j) {
      int s0 = __shfl(myidx, j);
      float w0 = __shfl(myw, j);
      unsigned a0 = hb32[(size_t)s0 * 64 + lane];
      ax = fmaf(bf_lo(a0), w0, ax); ay = fmaf(bf_hi(a0), w0, ay);
    }
  }
  float2 o; o.x = ax; o.y = ay;
  *(float2*)&out[(size_t)node * F + lane * 2] = o;
}

// ---- BN partial stats: per-feature sum / sumsq ----
__global__ __launch_bounds__(256) void k_stats(const float* __restrict__ out,
                                               float* __restrict__ stats, int n) {
  int f = threadIdx.x & (F - 1);
  int half = threadIdx.x >> 7;
  int rpb = (n + gridDim.x - 1) / gridDim.x;
  int r0 = blockIdx.x * rpb;
  int r1 = r0 + rpb; if (r1 > n) r1 = n;
  float s = 0.f, ss = 0.f;
  for (int r = r0 + half; r < r1; r += 2) {
    float v = out[(size_t)r * F + f];
    s += v; ss += v * v;
  }
  __shared__ float sh[2][F][2];
  sh[0][f][half] = s; sh[1][f][half] = ss;
  __syncthreads();
  if (half == 0) {
    atomicAdd(&stats[f], sh[0][f][0] + sh[0][f][1]);
    atomicAdd(&stats[F + f], sh[1][f][0] + sh[1][f][1]);
  }
}

// ---- apply BN + ReLU in place (scale/shift computed inline from stats) ----
__global__ __launch_bounds__(256) void k_apply(float* __restrict__ out,
                                               const float* __restrict__ stats,
                                               const float* __restrict__ gamma,
                                               const float* __restrict__ beta, int n) {
  long long i4 = (long long)blockIdx.x * 256 + threadIdx.x;
  if (i4 >= (long long)n * (F / 4)) return;
  int c0 = ((int)i4 & 31) * 4;
  float inv_n = 1.0f / (float)n;
  float4 v = *(const float4*)(out + i4 * 4);
  float r[4] = {v.x, v.y, v.z, v.w};
#pragma unroll
  for (int j = 0; j < 4; ++j) {
    int f = c0 + j;
    float mean = stats[f] * inv_n;
    float var = stats[F + f] * inv_n - mean * mean;
    float sc = gamma[f] * rsqrtf(var + EPSV);
    float sf = beta[f] - mean * sc;
    r[j] = fmaxf(r[j] * sc + sf, 0.f);
  }
  float4 o; o.x = r[0]; o.y = r[1]; o.z = r[2]; o.w = r[3];
  *(float4*)(out + i4 * 4) = o;
}

extern "C" void kernel_launch(void* const* d_in, const int* in_sizes, int n_in,
                              void* d_out, int out_size, void* d_ws, size_t ws_size,
                              hipStream_t stream) {
  const float* x     = (const float*)d_in[0];
  const int*   ei    = (const int*)d_in[1];
  const float* W     = (const float*)d_in[2];
  const float* b     = (const float*)d_in[3];
  const float* gamma = (const float*)d_in[4];
  const float* beta  = (const float*)d_in[5];
  int n = in_sizes[0] / F;
  int e = in_sizes[1] / 2;
  const int* row = ei;       // sources
  const int* col = ei + e;   // targets

  float* out = (float*)d_out;
  int nb = (n + 127) >> 7;

  // workspace layout
  char* wp = (char*)d_ws;
  unsigned short* hb = (unsigned short*)wp;            wp += (size_t)n * F * 2;
  float* dinv        = (float*)wp;                     wp += (size_t)n * 4;
  float* stats       = (float*)wp;                     wp += 512 * 4;
  int* deg           = (int*)wp;                       wp += (size_t)n * 4;
  int* bucketCnt     = (int*)wp;                       wp += NBMAX * 4;
  int* bucketBase    = (int*)wp;                       wp += (NBMAX + 1) * 4;
  int* gcur          = (int*)wp;                       wp += NBMAX * 4;
  int* rowptr        = (int*)wp;                       wp += (size_t)(n + 1) * 4;
  unsigned* pairs    = (unsigned*)wp;                  wp += (size_t)e * 4;
  int* srcs          = (int*)wp;                       wp += (size_t)e * 4;
  unsigned short* wt = (unsigned short*)wp;            wp += (size_t)F * F * 2;

  k_zero   <<<(n + 255) / 256, 256, 0, stream>>>(deg, bucketCnt, stats, n);
  k_degc   <<<(e + 255) / 256, 256, 0, stream>>>(col, deg, e);
  k_bsum   <<<nb, 128, 0, stream>>>(deg, bucketCnt, dinv, n);
  k_bscan  <<<1, 256, 0, stream>>>(bucketCnt, bucketBase, gcur, rowptr, e, nb, n);
  k_binfill<<<(e + CHUNK - 1) / CHUNK, 256, 0, stream>>>(row, col, gcur, pairs, e);
  k_sort2  <<<nb, 256, 0, stream>>>(bucketBase, pairs, deg, rowptr, srcs, n);
  k_wconv  <<<(F * F + 255) / 256, 256, 0, stream>>>(W, wt);
  k_gemm   <<<(n + 63) / 64, 256, 0, stream>>>(x, wt, hb, n);
  k_gather <<<(n + 3) / 4, 256, 0, stream>>>(rowptr, srcs, dinv, (const unsigned*)hb, b, out, n);
  k_stats  <<<512, 256, 0, stream>>>(out, stats, n);
  k_apply  <<<(int)(((long long)n * (F / 4) + 255) / 256), 256, 0, stream>>>(out, stats, gamma, beta, n);
}